// Round 5
// baseline (251.036 us; speedup 1.0000x reference)
//
#include <hip/hip_runtime.h>
#include <math.h>

#define BB   512
#define NN   512
#define MM   128
#define CC   1024
#define ADDR 134
#define EPSF 1e-8f

__device__ __forceinline__ float softplus_f(float x) {
    return fmaxf(x, 0.0f) + log1pf(expf(-fabsf(x)));
}

// ================= K1: fc + params, 2 batch rows per block =================
// grid 256, block 512. Each block computes b and b+256 (shares W_fc reads).
__global__ __launch_bounds__(512) void k1_fc(
    const float* __restrict__ co, const float* __restrict__ W_fc,
    const float* __restrict__ b_fc, float* __restrict__ ws_kk,
    float* __restrict__ ws_par)
{
    __shared__ __align__(16) float s_co0[CC];
    __shared__ __align__(16) float s_co1[CC];
    __shared__ float s_part0[4 * MM];
    __shared__ float s_part1[4 * MM];
    __shared__ float s_extra[2][8];
    __shared__ float s_red[2][2];
    __shared__ float s_scale[2];

    const int t  = threadIdx.x;
    const int b0 = blockIdx.x;
    const int b1 = blockIdx.x + 256;

    s_co0[t]       = co[(size_t)b0 * CC + t];
    s_co0[t + 512] = co[(size_t)b0 * CC + t + 512];
    s_co1[t]       = co[(size_t)b1 * CC + t];
    s_co1[t + 512] = co[(size_t)b1 * CC + t + 512];
    __syncthreads();

    {
        const int o    = t & (MM - 1);
        const int part = t >> 7;                 // 0..3, 256 C-values each
        const float* Wp = W_fc + o;
        float a0 = 0.f, a1 = 0.f, a2 = 0.f, a3 = 0.f;
        float d0 = 0.f, d1 = 0.f, d2 = 0.f, d3 = 0.f;
        const int cc0 = part * 256;
        for (int c = cc0; c < cc0 + 256; c += 4) {
            float w0 = Wp[(size_t)(c + 0) * ADDR];
            float w1 = Wp[(size_t)(c + 1) * ADDR];
            float w2 = Wp[(size_t)(c + 2) * ADDR];
            float w3 = Wp[(size_t)(c + 3) * ADDR];
            float4 u = *(const float4*)(s_co0 + c);
            float4 v = *(const float4*)(s_co1 + c);
            a0 = fmaf(u.x, w0, a0); a1 = fmaf(u.y, w1, a1);
            a2 = fmaf(u.z, w2, a2); a3 = fmaf(u.w, w3, a3);
            d0 = fmaf(v.x, w0, d0); d1 = fmaf(v.y, w1, d1);
            d2 = fmaf(v.z, w2, d2); d3 = fmaf(v.w, w3, d3);
        }
        s_part0[part * MM + o] = (a0 + a1) + (a2 + a3);
        s_part1[part * MM + o] = (d0 + d1) + (d2 + d3);

        const int wv = t >> 6;                   // 8 waves, 6 used for extras
        if (wv < 6) {
            const int ll = t & 63;
            const int oe = MM + wv;
            const float* We = W_fc + oe;
            float e0 = 0.f, e1 = 0.f;
            for (int c = ll; c < CC; c += 64) {
                float w = We[(size_t)c * ADDR];
                e0 = fmaf(s_co0[c], w, e0);
                e1 = fmaf(s_co1[c], w, e1);
            }
            #pragma unroll
            for (int off = 32; off >= 1; off >>= 1) {
                e0 += __shfl_xor(e0, off, 64);
                e1 += __shfl_xor(e1, off, 64);
            }
            if (ll == 0) {
                s_extra[0][wv] = e0 + b_fc[oe];
                s_extra[1][wv] = e1 + b_fc[oe];
            }
        }
    }
    __syncthreads();

    float k0 = 0.f, k1v = 0.f;
    if (t < MM) {
        float bias = b_fc[t];
        k0  = bias + s_part0[t] + s_part0[MM + t] + s_part0[2 * MM + t] + s_part0[3 * MM + t];
        k1v = bias + s_part1[t] + s_part1[MM + t] + s_part1[2 * MM + t] + s_part1[3 * MM + t];
        float v0 = k0 * k0, v1 = k1v * k1v;
        #pragma unroll
        for (int off = 32; off >= 1; off >>= 1) {
            v0 += __shfl_xor(v0, off, 64);
            v1 += __shfl_xor(v1, off, 64);
        }
        if ((t & 63) == 0) { s_red[0][t >> 6] = v0; s_red[1][t >> 6] = v1; }
    }
    __syncthreads();
    if (t < 2) {
        const int bs = t;
        const int bb = bs ? b1 : b0;
        float ks = s_red[bs][0] + s_red[bs][1];
        float norm_k = sqrtf(ks) + EPSF;
        float beta = softplus_f(s_extra[bs][0]);
        float g = 1.0f / (1.0f + expf(-s_extra[bs][1]));
        float e0 = s_extra[bs][2], e1 = s_extra[bs][3], e2 = s_extra[bs][4];
        float mx = fmaxf(e0, fmaxf(e1, e2));
        float x0 = expf(e0 - mx), x1 = expf(e1 - mx), x2 = expf(e2 - mx);
        float inv = 1.0f / (x0 + x1 + x2);
        s_scale[bs] = beta / norm_k;
        float* pp = ws_par + (size_t)bb * 8;
        pp[0] = g;
        pp[1] = x0 * inv; pp[2] = x1 * inv; pp[3] = x2 * inv;
        pp[4] = 1.0f + softplus_f(s_extra[bs][5]);
    }
    __syncthreads();
    if (t < MM) {
        ws_kk[(size_t)b0 * MM + t] = k0  * s_scale[0];
        ws_kk[(size_t)b1 * MM + t] = k1v * s_scale[1];
    }
}

// ================= K2: beta*cosine-sim, pure stream, zero barriers =================
// grid 2048 (= 512 b x 4 tiles of 128 rows), block 256 (8 groups of 32 lanes).
// kk already carries beta/||k||, so bsim = (kk . row) / (||row|| + eps).
__global__ __launch_bounds__(256) void k2_sim(
    const float* __restrict__ mem, const float* __restrict__ ws_kk,
    float* __restrict__ ws_bsim)
{
    const int bb   = blockIdx.x;
    const int b    = bb >> 2;
    const int tile = bb & 3;
    const int t = threadIdx.x;
    const int g = t >> 5;
    const int l = t & 31;
    const float4* memb = (const float4*)(mem + (size_t)b * NN * MM) + (size_t)tile * 128 * 32;
    const float4 kv = ((const float4*)(ws_kk + (size_t)b * MM))[l];
    float* bs = ws_bsim + (size_t)b * NN + tile * 128;

    #pragma unroll
    for (int j = 0; j < 16; j += 4) {
        float4 a0 = memb[(size_t)(g + (j + 0) * 8) * 32 + l];
        float4 a1 = memb[(size_t)(g + (j + 1) * 8) * 32 + l];
        float4 a2 = memb[(size_t)(g + (j + 2) * 8) * 32 + l];
        float4 a3 = memb[(size_t)(g + (j + 3) * 8) * 32 + l];

        float d0 = a0.x*kv.x + a0.y*kv.y + a0.z*kv.z + a0.w*kv.w;
        float d1 = a1.x*kv.x + a1.y*kv.y + a1.z*kv.z + a1.w*kv.w;
        float d2 = a2.x*kv.x + a2.y*kv.y + a2.z*kv.z + a2.w*kv.w;
        float d3 = a3.x*kv.x + a3.y*kv.y + a3.z*kv.z + a3.w*kv.w;
        float q0 = a0.x*a0.x + a0.y*a0.y + a0.z*a0.z + a0.w*a0.w;
        float q1 = a1.x*a1.x + a1.y*a1.y + a1.z*a1.z + a1.w*a1.w;
        float q2 = a2.x*a2.x + a2.y*a2.y + a2.z*a2.z + a2.w*a2.w;
        float q3 = a3.x*a3.x + a3.y*a3.y + a3.z*a3.z + a3.w*a3.w;

        // fold tree (verified rounds 3-4): 17 shfl per 4 rows
        d0 += __shfl_xor(d0, 16, 64); q0 += __shfl_xor(q0, 16, 64);
        d1 += __shfl_xor(d1, 16, 64); q1 += __shfl_xor(q1, 16, 64);
        d2 += __shfl_xor(d2, 16, 64); q2 += __shfl_xor(q2, 16, 64);
        d3 += __shfl_xor(d3, 16, 64); q3 += __shfl_xor(q3, 16, 64);
        float W0 = (l & 16) ? q0 : d0;
        float W1 = (l & 16) ? q1 : d1;
        float W2 = (l & 16) ? q2 : d2;
        float W3 = (l & 16) ? q3 : d3;
        W0 += __shfl_xor(W0, 8, 64); W1 += __shfl_xor(W1, 8, 64);
        W2 += __shfl_xor(W2, 8, 64); W3 += __shfl_xor(W3, 8, 64);
        float X0 = (l & 8) ? W1 : W0;
        float X1 = (l & 8) ? W3 : W2;
        X0 += __shfl_xor(X0, 4, 64); X1 += __shfl_xor(X1, 4, 64);
        float Y = (l & 4) ? X1 : X0;
        Y += __shfl_xor(Y, 2, 64);
        Y += __shfl_xor(Y, 1, 64);
        float Q = __shfl_xor(Y, 16, 64);
        if (l < 16 && (l & 3) == 0) {
            int jj = j + ((l & 4) >> 1) + ((l & 8) >> 3);
            bs[g + jj * 8] = Y / (sqrtf(Q) + EPSF);
        }
    }
}

// ================= K3: softmax -> gate -> shift -> sharpen -> read_vec =================
// grid 512, block 1024 (32 groups of 32 lanes for pass 2).
__global__ __launch_bounds__(1024) void k3_tail(
    const float* __restrict__ prev_w, const float* __restrict__ mem,
    const float* __restrict__ ws_bsim, const float* __restrict__ ws_par,
    float* __restrict__ out_rv, float* __restrict__ out_w)
{
    __shared__ float s_wg[NN];
    __shared__ float s_w[NN];
    __shared__ __align__(16) float s_part[32 * MM];  // 16 KB
    __shared__ float s_scr[4 * MM];
    __shared__ float s_red[16];

    const int t = threadIdx.x;
    const int b = blockIdx.x;
    const int gi = t >> 5;
    const int l  = t & 31;
    const float4* memb = (const float4*)(mem + (size_t)b * NN * MM);

    float pw = (t < NN) ? prev_w[(size_t)b * NN + t] : 0.0f;
    const float NEG = -3.0e38f;
    float b1 = (t < NN) ? ws_bsim[(size_t)b * NN + t] : NEG;
    const float g     = ws_par[(size_t)b * 8 + 0];
    const float sh0   = ws_par[(size_t)b * 8 + 1];
    const float sh1   = ws_par[(size_t)b * 8 + 2];
    const float sh2   = ws_par[(size_t)b * 8 + 3];
    const float gamma = ws_par[(size_t)b * 8 + 4];

    // softmax max
    float m = b1;
    #pragma unroll
    for (int off = 32; off >= 1; off >>= 1) m = fmaxf(m, __shfl_xor(m, off, 64));
    if ((t & 63) == 0) s_red[t >> 6] = m;
    __syncthreads();
    float M8 = s_red[0];
    #pragma unroll
    for (int i = 1; i < 8; ++i) M8 = fmaxf(M8, s_red[i]);
    __syncthreads();

    // softmax sum
    float e1 = (t < NN) ? expf(b1 - M8) : 0.0f;
    float ls = e1;
    #pragma unroll
    for (int off = 32; off >= 1; off >>= 1) ls += __shfl_xor(ls, off, 64);
    if ((t & 63) == 0) s_red[t >> 6] = ls;
    __syncthreads();
    float S = s_red[0];
    #pragma unroll
    for (int i = 1; i < 8; ++i) S += s_red[i];
    __syncthreads();

    // gate
    const float invS = 1.0f / S;
    float wg1 = fmaf(g, e1 * invS, (1.0f - g) * pw);
    if (t < NN) s_wg[t] = wg1;
    __syncthreads();

    // shift + sharpen (normalization deferred to outputs)
    float wp1 = 0.0f;
    if (t < NN) {
        float ws1 = sh0 * s_wg[(t + NN - 1) & (NN - 1)]
                  + sh1 * wg1
                  + sh2 * s_wg[(t + 1) & (NN - 1)];
        wp1 = powf(ws1, gamma);
        s_w[t] = wp1;
    }
    __syncthreads();

    // pass 2: unnormalized read_vec from mem (LLC-resident after K2), Z alongside
    float4 acc = make_float4(0.f, 0.f, 0.f, 0.f);
    for (int j = 0; j < 16; j += 4) {
        float4 a0 = memb[(size_t)(gi + (j + 0) * 32) * 32 + l];
        float4 a1 = memb[(size_t)(gi + (j + 1) * 32) * 32 + l];
        float4 a2 = memb[(size_t)(gi + (j + 2) * 32) * 32 + l];
        float4 a3 = memb[(size_t)(gi + (j + 3) * 32) * 32 + l];
        float w0 = s_w[gi + (j + 0) * 32];
        float w1 = s_w[gi + (j + 1) * 32];
        float w2 = s_w[gi + (j + 2) * 32];
        float w3 = s_w[gi + (j + 3) * 32];
        acc.x = fmaf(w0, a0.x, acc.x); acc.y = fmaf(w0, a0.y, acc.y);
        acc.z = fmaf(w0, a0.z, acc.z); acc.w = fmaf(w0, a0.w, acc.w);
        acc.x = fmaf(w1, a1.x, acc.x); acc.y = fmaf(w1, a1.y, acc.y);
        acc.z = fmaf(w1, a1.z, acc.z); acc.w = fmaf(w1, a1.w, acc.w);
        acc.x = fmaf(w2, a2.x, acc.x); acc.y = fmaf(w2, a2.y, acc.y);
        acc.z = fmaf(w2, a2.z, acc.z); acc.w = fmaf(w2, a2.w, acc.w);
        acc.x = fmaf(w3, a3.x, acc.x); acc.y = fmaf(w3, a3.y, acc.y);
        acc.z = fmaf(w3, a3.z, acc.z); acc.w = fmaf(w3, a3.w, acc.w);
    }

    float lz = wp1;
    #pragma unroll
    for (int off = 32; off >= 1; off >>= 1) lz += __shfl_xor(lz, off, 64);
    if ((t & 63) == 0) s_red[t >> 6] = lz;

    *((float4*)&s_part[gi * MM + l * 4]) = acc;
    __syncthreads();

    float Z = s_red[0];
    #pragma unroll
    for (int i = 1; i < 8; ++i) Z += s_red[i];
    const float invZ = 1.0f / (Z + EPSF);

    if (t < NN) out_w[(size_t)b * NN + t] = wp1 * invZ;

    if (t < 512) {
        const int h = t >> 7;
        const int o = t & (MM - 1);
        float r = 0.f;
        #pragma unroll
        for (int q = 0; q < 8; ++q) r += s_part[(h * 8 + q) * MM + o];
        s_scr[h * MM + o] = r;
    }
    __syncthreads();
    if (t < MM) {
        float r = s_scr[t] + s_scr[MM + t] + s_scr[2 * MM + t] + s_scr[3 * MM + t];
        out_rv[(size_t)b * MM + t] = r * invZ;
    }
}

extern "C" void kernel_launch(void* const* d_in, const int* in_sizes, int n_in,
                              void* d_out, int out_size, void* d_ws, size_t ws_size,
                              hipStream_t stream) {
    const float* co     = (const float*)d_in[0];
    const float* prev_w = (const float*)d_in[1];
    const float* mem    = (const float*)d_in[2];
    const float* W_fc   = (const float*)d_in[3];
    const float* b_fc   = (const float*)d_in[4];
    float* out = (float*)d_out;

    float* ws      = (float*)d_ws;
    float* ws_kk   = ws;                       // 512*128        = 65536 floats
    float* ws_par  = ws + 65536;               // 512*8          =  4096 floats
    float* ws_bsim = ws + 65536 + 4096;        // 512*512        = 262144 floats

    k1_fc  <<<256,  512, 0, stream>>>(co, W_fc, b_fc, ws_kk, ws_par);
    k2_sim <<<2048, 256, 0, stream>>>(mem, ws_kk, ws_bsim);
    k3_tail<<<512, 1024, 0, stream>>>(prev_w, mem, ws_bsim, ws_par,
                                      out, out + (size_t)BB * MM);
}